// Round 9
// baseline (484.910 us; speedup 1.0000x reference)
//
#include <hip/hip_runtime.h>
#include <hip/hip_bf16.h>
#include <math.h>

// ---------------- problem constants ----------------
#define B_   16
#define S_   1024
#define CIN  1280
#define D_   512
#define H_   8
#define HD_  64
#define NROW (B_ * S_)        // 16384

typedef __bf16 bf16;
typedef float  f32x2  __attribute__((ext_vector_type(2)));
typedef float  f32x4  __attribute__((ext_vector_type(4)));
typedef bf16   bf16x4 __attribute__((ext_vector_type(4)));
typedef bf16   bf16x8 __attribute__((ext_vector_type(8)));

__device__ __forceinline__ void gload_lds16(const bf16* g, bf16* l) {
    __builtin_amdgcn_global_load_lds(
        (const __attribute__((address_space(1))) void*)g,
        (__attribute__((address_space(3))) void*)l, 16, 0, 0);
}

#define SBAR()   __builtin_amdgcn_s_barrier()
#define SCHED0() __builtin_amdgcn_sched_barrier(0)
#define VMCNT8() asm volatile("s_waitcnt vmcnt(8)" ::: "memory")
#define VMCNT0() asm volatile("s_waitcnt vmcnt(0)" ::: "memory")

// ---------------- merged preamble: cvt(x) + 5 weight transposes + cs table ----
__device__ __forceinline__ void tr_tile(const float* __restrict__ in,
                                        bf16* __restrict__ out,
                                        int R, int C, int cx, int ry, int t)
{
    __shared__ float T[32][33];
    const int r0 = ry << 5, c0 = cx << 5;
    {
        int lr = t >> 3, lc = (t & 7) << 2;
        f32x4 v = *(const f32x4*)(in + (size_t)(r0 + lr) * C + c0 + lc);
        T[lr][lc] = v[0]; T[lr][lc + 1] = v[1]; T[lr][lc + 2] = v[2]; T[lr][lc + 3] = v[3];
    }
    __syncthreads();
    {
        int oc = t >> 3, orr = (t & 7) << 2;
        bf16x4 o;
        o[0] = (bf16)T[orr][oc];     o[1] = (bf16)T[orr + 1][oc];
        o[2] = (bf16)T[orr + 2][oc]; o[3] = (bf16)T[orr + 3][oc];
        *(bf16x4*)(out + (size_t)(c0 + oc) * R + r0 + orr) = o;
    }
}

#define NCVT (NROW * CIN / 4 / 256)   // 20480 blocks for x cvt

__global__ __launch_bounds__(256)
void prep_kernel(const float* __restrict__ x, bf16* __restrict__ x_b,
                 const float* __restrict__ w_in,   bf16* __restrict__ win_t,
                 const float* __restrict__ w_qkv,  bf16* __restrict__ wqkv_t,
                 const float* __restrict__ w_out,  bf16* __restrict__ wout_t,
                 const float* __restrict__ w_ffn1, bf16* __restrict__ wf1_t,
                 const float* __restrict__ w_ffn2, bf16* __restrict__ wf2_t,
                 float* __restrict__ cs)
{
    const int t   = threadIdx.x;
    int bid = blockIdx.x;
    if (bid < NCVT) {
        int i = bid * 256 + t;
        f32x4 v = *(const f32x4*)(x + (size_t)i * 4);
        bf16x4 o;
        o[0] = (bf16)v[0]; o[1] = (bf16)v[1]; o[2] = (bf16)v[2]; o[3] = (bf16)v[3];
        *(bf16x4*)(x_b + (size_t)i * 4) = o;
        return;
    }
    bid -= NCVT;
    if (bid < 640)  { tr_tile(w_in,   win_t,  1280, 512,  bid % 16, bid / 16, t); return; }
    bid -= 640;
    if (bid < 768)  { tr_tile(w_qkv,  wqkv_t, 512,  1536, bid % 48, bid / 48, t); return; }
    bid -= 768;
    if (bid < 256)  { tr_tile(w_out,  wout_t, 512,  512,  bid % 16, bid / 16, t); return; }
    bid -= 256;
    if (bid < 1024) { tr_tile(w_ffn1, wf1_t,  512,  2048, bid % 64, bid / 64, t); return; }
    bid -= 1024;
    if (bid < 1024) { tr_tile(w_ffn2, wf2_t,  2048, 512,  bid % 16, bid / 16, t); return; }
    bid -= 1024;
    {   // cs table: 128 blocks
        int idx = bid * 256 + t;              // 0..32767
        int s = idx >> 5, i = idx & 31;
        float freq = exp2f(-(float)i * (13.287712379549449f / 32.f));
        float sn, c;
        sincosf((float)s * freq, &sn, &c);
        cs[(size_t)idx * 2]     = c;
        cs[(size_t)idx * 2 + 1] = sn;
    }
}
#define NPREP (NCVT + 640 + 768 + 256 + 1024 + 1024 + 128)

// ---------------- 128x128 BK=64 double-buffered GEMM (ALL five GEMMs) ----------------
#define ASZ1 (128 * 64)

template<int EPI, bool RELU, bool RES, bool OUTF, bool OUTB>
__global__ __launch_bounds__(256, 2)
void gemm128_kernel(const bf16* __restrict__ A, const bf16* __restrict__ Wt,
                    const float* __restrict__ bias, const bf16* __restrict__ res,
                    float* __restrict__ outf, bf16* __restrict__ outb,
                    const float* __restrict__ cs, bf16* __restrict__ vt,
                    int M, int N, int K)
{
    __shared__ bf16 lds[4 * ASZ1];   // A dbuf (2) + B dbuf (2), 64 KiB

    const int tid  = threadIdx.x;
    const int lane = tid & 63;
    const int wid  = tid >> 6;

    const int perX = (M >> 7) >> 3;            // 16
    const int lin  = blockIdx.x;
    const int idx  = lin >> 3;
    const int my   = (lin & 7) * perX + (idx & (perX - 1));
    const int nx   = idx / perX;
    const int m0   = my << 7, n0 = nx << 7;

    const int sRow = lane >> 3;
    const int sK   = ((lane & 7) ^ sRow) << 3;

    const int r2  = wid >> 1;
    const int c2  = wid & 1;
    const int cc  = lane & 15;
    const int g   = (lane >> 4) & 3;
    const int swz = (cc & 7) << 4;

    f32x4 acc[4][4] = {};

    auto stage = [&](int t, int b) {
        const bf16* gA = A  + (size_t)m0 * K + t * 64;
        const bf16* gB = Wt + (size_t)n0 * K + t * 64;
        bf16* lA = lds + b * ASZ1;
        bf16* lB = lds + 2 * ASZ1 + b * ASZ1;
        #pragma unroll
        for (int v = 0; v < 4; ++v) {
            const int ch = v * 4 + wid;
            gload_lds16(gA + (size_t)(ch * 8 + sRow) * K + sK, lA + ch * 512);
            gload_lds16(gB + (size_t)(ch * 8 + sRow) * K + sK, lB + ch * 512);
        }
    };

    const int T = K >> 6;
    stage(0, 0);
    stage(1, 1);
    VMCNT8();
    SCHED0();
    SBAR();

    for (int t = 0; t < T; ++t) {
        const int b = t & 1;
        const char* lA = (const char*)(lds + b * ASZ1);
        const char* lB = (const char*)(lds + 2 * ASZ1 + b * ASZ1);

        #pragma unroll
        for (int ks = 0; ks < 2; ++ks) {
            bf16x8 af[4], bfr[4];
            #pragma unroll
            for (int i = 0; i < 4; ++i) {
                const int row = r2 * 64 + i * 16 + cc;
                af[i] = *(const bf16x8*)(lA + row * 128 + ((ks * 64 + g * 16) ^ swz));
            }
            #pragma unroll
            for (int j = 0; j < 4; ++j) {
                const int row = c2 * 64 + j * 16 + cc;
                bfr[j] = *(const bf16x8*)(lB + row * 128 + ((ks * 64 + g * 16) ^ swz));
            }
            __builtin_amdgcn_s_setprio(1);
            #pragma unroll
            for (int i = 0; i < 4; ++i)
                #pragma unroll
                for (int j = 0; j < 4; ++j)
                    acc[i][j] = __builtin_amdgcn_mfma_f32_16x16x32_bf16(af[i], bfr[j], acc[i][j], 0, 0, 0);
            __builtin_amdgcn_s_setprio(0);
        }
        SCHED0();
        SBAR();
        if (t + 2 < T) {
            stage(t + 2, b);
            VMCNT8();
        } else if (t + 1 < T) {
            VMCNT0();
        }
        if (t + 1 < T) { SCHED0(); SBAR(); }
    }

    const int rq = g << 2;
    if constexpr (EPI == 1) {
        const int colb = c2 * 64;
        if (nx < 8) {
            float bj[4];
            #pragma unroll
            for (int j = 0; j < 4; ++j) bj[j] = bias[n0 + colb + j * 16 + cc];
            #pragma unroll
            for (int i = 0; i < 4; ++i) {
                #pragma unroll
                for (int r = 0; r < 4; ++r) {
                    const int gm = m0 + r2 * 64 + i * 16 + rq + r;
                    const int s  = gm & (S_ - 1);
                    #pragma unroll
                    for (int jp = 0; jp < 2; ++jp) {
                        const int d = jp * 16 + cc;
                        f32x2 csv = *(const f32x2*)(cs + ((size_t)s * 32 + d) * 2);
                        float x1 = acc[i][jp][r]     + bj[jp];
                        float x2 = acc[i][jp + 2][r] + bj[jp + 2];
                        const size_t o1 = (size_t)gm * N + n0 + colb + d;
                        outb[o1]      = (bf16)(x1 * csv[0] - x2 * csv[1]);
                        outb[o1 + 32] = (bf16)(x1 * csv[1] + x2 * csv[0]);
                    }
                }
            }
        } else {
            const int col0 = n0 + colb;
            const int hw = (col0 >> 6) & 7;
            const int bb = m0 >> 10;
            bf16* vbase = vt + (size_t)(bb * 8 + hw) * (HD_ * S_);
            const int sb0 = (m0 & (S_ - 1)) + r2 * 64 + rq;
            #pragma unroll
            for (int i = 0; i < 4; ++i) {
                #pragma unroll
                for (int j = 0; j < 4; ++j) {
                    const int d = j * 16 + cc;
                    const float bv = bias[col0 + d];
                    bf16x4 pk;
                    #pragma unroll
                    for (int r = 0; r < 4; ++r) pk[r] = (bf16)(acc[i][j][r] + bv);
                    *(bf16x4*)(vbase + (size_t)d * S_ + sb0 + i * 16) = pk;
                }
            }
        }
    } else {
        #pragma unroll
        for (int i = 0; i < 4; ++i) {
            #pragma unroll
            for (int j = 0; j < 4; ++j) {
                const int gn = n0 + c2 * 64 + j * 16 + cc;
                const float bv = bias[gn];
                #pragma unroll
                for (int r = 0; r < 4; ++r) {
                    const int gm = m0 + r2 * 64 + i * 16 + rq + r;
                    float v = acc[i][j][r] + bv;
                    if (RES)  v += (float)res[(size_t)gm * N + gn];
                    if (RELU) v = fmaxf(v, 0.f);
                    if (OUTF) outf[(size_t)gm * N + gn] = v;
                    if (OUTB) outb[(size_t)gm * N + gn] = (bf16)v;
                }
            }
        }
    }
    (void)cs; (void)vt;
}

// ---------------- MFMA flash attention v6: no K/V staging, no barriers ----
// K/V tiles are L2-resident (256 KB per bh; bh-major grid keeps them on one
// XCD) and L1-shared across the block's 8 waves. Fragments are 16B-contiguous
// per lane straight from global -> staging + all barriers deleted. LDS holds
// only the per-wave Ps bounce (18.4 KB) -> ~3 resident blocks/CU of TLP.
// l via ones-column MFMA; defer-max THR=8 lg2; fma-folded exp2. QBLK=128.
#define PST 72

__global__ __launch_bounds__(512, 6)
void attn_kernel(const bf16* __restrict__ qkv, const bf16* __restrict__ vtg,
                 bf16* __restrict__ o)
{
    __shared__ bf16 Ps[8][16 * PST];

    const int bh  = blockIdx.x;
    const int b   = bh >> 3;
    const int h   = bh & 7;
    const int q0  = blockIdx.y << 7;
    const int tid = threadIdx.x;
    const int lane = tid & 63;
    const int w    = tid >> 6;
    const int c    = lane & 15;
    const int g    = lane >> 4;

    const size_t rs = 3 * D_;
    const bf16* qb = qkv + (size_t)b * S_ * rs + h * HD_;
    const bf16* kb = qb + D_;
    const bf16* vt = vtg + (size_t)bh * HD_ * S_;

    bf16x8 qf[2];
    {
        const bf16* qrow = qb + (size_t)(q0 + w * 16 + c) * rs + g * 8;
        qf[0] = *(const bf16x8*)(qrow);
        qf[1] = *(const bf16x8*)(qrow + 32);
    }

    bf16x8 vones;
    {
        bf16 one = (bf16)(c == 0 ? 1.f : 0.f);
        #pragma unroll
        for (int u = 0; u < 8; ++u) vones[u] = one;
    }

    f32x4 oa[4] = {};
    f32x4 oa5 = {};                          // l rides in col 0 (c==0 lanes)
    float m_r = -3.0e38f;
    const float CE  = 0.18033688011112042f;  // (1/8)*log2(e)
    const float THR = 44.3614195558365f;     // 8 / CE

    for (int t = 0; t < 16; ++t) {
        // QK^T (swapped): S^T[key][q], frags straight from global (L1/L2)
        f32x4 sa[4] = {};
        const bf16* kt = kb + (size_t)t * 64 * rs;
        __builtin_amdgcn_s_setprio(1);
        #pragma unroll
        for (int ch = 0; ch < 2; ++ch)
            #pragma unroll
            for (int ks = 0; ks < 4; ++ks) {
                bf16x8 kf = *(const bf16x8*)(kt + (size_t)(ks * 16 + c) * rs + ch * 32 + g * 8);
                sa[ks] = __builtin_amdgcn_mfma_f32_16x16x32_bf16(kf, qf[ch], sa[ks], 0, 0, 0);
            }
        __builtin_amdgcn_s_setprio(0);

        float pmax = -3.0e38f;
        #pragma unroll
        for (int ks = 0; ks < 4; ++ks)
            pmax = fmaxf(pmax, fmaxf(fmaxf(sa[ks][0], sa[ks][1]), fmaxf(sa[ks][2], sa[ks][3])));
        pmax = fmaxf(pmax, __shfl_xor(pmax, 16, 64));
        pmax = fmaxf(pmax, __shfl_xor(pmax, 32, 64));

        if (!__all(pmax - m_r <= THR)) {
            float mnew = fmaxf(m_r, pmax);
            float sc = __builtin_amdgcn_exp2f((m_r - mnew) * CE);
            #pragma unroll
            for (int r = 0; r < 4; ++r) {
                float scr = __shfl(sc, g * 4 + r, 64);
                #pragma unroll
                for (int j = 0; j < 4; ++j) oa[j][r] *= scr;
                oa5[r] *= scr;
            }
            m_r = mnew;
        }

        const float nmCE = -m_r * CE;
        #pragma unroll
        for (int ks = 0; ks < 4; ++ks) {
            bf16x4 pb;
            #pragma unroll
            for (int r = 0; r < 4; ++r)
                pb[r] = (bf16)__builtin_amdgcn_exp2f(__builtin_fmaf(sa[ks][r], CE, nmCE));
            *(bf16x4*)&Ps[w][c * PST + ks * 16 + g * 4] = pb;
        }

        // PV: A = P[q][key] (per-wave LDS), B = V^T[d][key] from global
        const bf16* vtt = vt + t * 64;
        __builtin_amdgcn_s_setprio(1);
        #pragma unroll
        for (int ch = 0; ch < 2; ++ch) {
            bf16x8 pa = *(const bf16x8*)&Ps[w][c * PST + ch * 32 + g * 8];
            #pragma unroll
            for (int j = 0; j < 4; ++j) {
                bf16x8 vf = *(const bf16x8*)(vtt + (size_t)(j * 16 + c) * S_ + ch * 32 + g * 8);
                oa[j] = __builtin_amdgcn_mfma_f32_16x16x32_bf16(pa, vf, oa[j], 0, 0, 0);
            }
            oa5 = __builtin_amdgcn_mfma_f32_16x16x32_bf16(pa, vones, oa5, 0, 0, 0);
        }
        __builtin_amdgcn_s_setprio(0);
    }

    float linv[4];
    #pragma unroll
    for (int r = 0; r < 4; ++r)
        linv[r] = 1.f / __shfl(oa5[r], lane & 48, 64);   // l from (c=0, same g)
    #pragma unroll
    for (int j = 0; j < 4; ++j)
        #pragma unroll
        for (int r = 0; r < 4; ++r) {
            int q = q0 + w * 16 + g * 4 + r;
            o[((size_t)(b * S_) + q) * D_ + h * HD_ + j * 16 + c] = (bf16)(oa[j][r] * linv[r]);
        }
}

// ---------------- LayerNorm over D=512, one wave per row ----------------
template<bool OUTF, bool OUTB>
__global__ __launch_bounds__(256)
void ln_kernel(const float* __restrict__ in, const float* __restrict__ g,
               const float* __restrict__ be, float* __restrict__ outf,
               bf16* __restrict__ outb)
{
    const int row  = (blockIdx.x << 2) + (threadIdx.x >> 6);
    const int lane = threadIdx.x & 63;
    const float* p = in + (size_t)row * D_;
    f32x4 a  = *(const f32x4*)(p + lane * 4);
    f32x4 b2 = *(const f32x4*)(p + 256 + lane * 4);
    float s  = a[0] + a[1] + a[2] + a[3] + b2[0] + b2[1] + b2[2] + b2[3];
    float s2 = a[0]*a[0] + a[1]*a[1] + a[2]*a[2] + a[3]*a[3]
             + b2[0]*b2[0] + b2[1]*b2[1] + b2[2]*b2[2] + b2[3]*b2[3];
    #pragma unroll
    for (int off = 32; off; off >>= 1) {
        s  += __shfl_xor(s,  off, 64);
        s2 += __shfl_xor(s2, off, 64);
    }
    const float mean = s * (1.f / 512.f);
    const float var  = s2 * (1.f / 512.f) - mean * mean;
    const float rstd = rsqrtf(var + 1e-5f);

    f32x4 g0 = *(const f32x4*)(g + lane * 4);
    f32x4 g1 = *(const f32x4*)(g + 256 + lane * 4);
    f32x4 e0 = *(const f32x4*)(be + lane * 4);
    f32x4 e1 = *(const f32x4*)(be + 256 + lane * 4);
    f32x4 o0, o1;
    #pragma unroll
    for (int u = 0; u < 4; u++) {
        o0[u] = (a[u]  - mean) * rstd * g0[u] + e0[u];
        o1[u] = (b2[u] - mean) * rstd * g1[u] + e1[u];
    }
    if (OUTF) {
        float* of = outf + (size_t)row * D_;
        *(f32x4*)(of + lane * 4)       = o0;
        *(f32x4*)(of + 256 + lane * 4) = o1;
    }
    if (OUTB) {
        bf16x4 c0, c1;
        #pragma unroll
        for (int u = 0; u < 4; u++) { c0[u] = (bf16)o0[u]; c1[u] = (bf16)o1[u]; }
        bf16* ob = outb + (size_t)row * D_;
        *(bf16x4*)(ob + lane * 4)       = c0;
        *(bf16x4*)(ob + 256 + lane * 4) = c1;
    }
}

// ---------------- host launcher ----------------
extern "C" void kernel_launch(void* const* d_in, const int* in_sizes, int n_in,
                              void* d_out, int out_size, void* d_ws, size_t ws_size,
                              hipStream_t stream)
{
    const float* x      = (const float*)d_in[0];
    const float* w_in   = (const float*)d_in[1];
    const float* b_in   = (const float*)d_in[2];
    const float* w_qkv  = (const float*)d_in[3];
    const float* b_qkv  = (const float*)d_in[4];
    const float* w_out  = (const float*)d_in[5];
    const float* b_out  = (const float*)d_in[6];
    const float* w_ffn1 = (const float*)d_in[7];
    const float* b_ffn1 = (const float*)d_in[8];
    const float* w_ffn2 = (const float*)d_in[9];
    const float* b_ffn2 = (const float*)d_in[10];
    const float* g1     = (const float*)d_in[11];
    const float* bn1    = (const float*)d_in[12];
    const float* g2     = (const float*)d_in[13];
    const float* bn2    = (const float*)d_in[14];

    char* ws = (char*)d_ws;
    constexpr size_t OFF_XB   = 0;
    constexpr size_t OFF_WIN  = OFF_XB   + 41943040ull;
    constexpr size_t OFF_WQKV = OFF_WIN  + 1310720ull;
    constexpr size_t OFF_WOUT = OFF_WQKV + 1572864ull;
    constexpr size_t OFF_WF1  = OFF_WOUT + 524288ull;
    constexpr size_t OFF_WF2  = OFF_WF1  + 2097152ull;
    constexpr size_t OFF_CS   = OFF_WF2  + 2097152ull;
    constexpr size_t OFF_HB   = OFF_CS   + 33554432ull;
    constexpr size_t OFF_QKV  = OFF_HB   + 16777216ull;
    constexpr size_t OFF_OB   = OFF_QKV  + 50331648ull;
    constexpr size_t OFF_VT   = OFF_OB   + 16777216ull;
    constexpr size_t OFF_H2B  = OFF_VT   + 33554432ull;
    constexpr size_t OFF_F1   = OFF_H2B  + 16777216ull;
    constexpr size_t OFF_T1   = OFF_XB;
    constexpr size_t OFF_T2   = OFF_QKV;

    bf16*  x_b    = (bf16*)(ws + OFF_XB);
    bf16*  win_t  = (bf16*)(ws + OFF_WIN);
    bf16*  wqkv_t = (bf16*)(ws + OFF_WQKV);
    bf16*  wout_t = (bf16*)(ws + OFF_WOUT);
    bf16*  wf1_t  = (bf16*)(ws + OFF_WF1);
    bf16*  wf2_t  = (bf16*)(ws + OFF_WF2);
    float* cs_t   = (float*)(ws + OFF_CS);
    bf16*  h_b    = (bf16*)(ws + OFF_HB);
    bf16*  qkv_b  = (bf16*)(ws + OFF_QKV);
    bf16*  o_b    = (bf16*)(ws + OFF_OB);
    bf16*  vt_g   = (bf16*)(ws + OFF_VT);
    bf16*  h2_b   = (bf16*)(ws + OFF_H2B);
    bf16*  f1_b   = (bf16*)(ws + OFF_F1);
    float* t1_f   = (float*)(ws + OFF_T1);
    float* t2_f   = (float*)(ws + OFF_T2);

    // merged preamble (1 launch)
    prep_kernel<<<NPREP, 256, 0, stream>>>(x, x_b, w_in, win_t, w_qkv, wqkv_t,
                                           w_out, wout_t, w_ffn1, wf1_t,
                                           w_ffn2, wf2_t, cs_t);

    // G1: h = x @ w_in + b_in -> bf16
    gemm128_kernel<0,false,false,false,true><<<(NROW/128) * (D_/128), 256, 0, stream>>>(
        x_b, win_t, b_in, nullptr, nullptr, h_b, nullptr, nullptr, NROW, D_, CIN);
    // G2: qkv = h @ w_qkv + b_qkv; fused RoPE(q,k)->qkv_b, v->vt_g
    gemm128_kernel<1,false,false,false,true><<<(NROW/128) * (3*D_/128), 256, 0, stream>>>(
        h_b, wqkv_t, b_qkv, nullptr, nullptr, qkv_b, cs_t, vt_g, NROW, 3*D_, D_);
    // attention -> o bf16   (QBLK=128, barrier-free, L2-resident K/V)
    attn_kernel<<<dim3(B_*H_, S_/128), 512, 0, stream>>>(qkv_b, vt_g, o_b);
    // G3: t1 = o @ w_out + b_out + h(bf16) -> f32
    gemm128_kernel<0,false,true,true,false><<<(NROW/128) * (D_/128), 256, 0, stream>>>(
        o_b, wout_t, b_out, h_b, t1_f, nullptr, nullptr, nullptr, NROW, D_, D_);
    // LN1 -> h2 bf16
    ln_kernel<false,true><<<NROW/4, 256, 0, stream>>>(t1_f, g1, bn1, nullptr, h2_b);
    // G4: f1 = relu(h2 @ w_ffn1 + b_ffn1) -> bf16
    gemm128_kernel<0,true,false,false,true><<<(NROW/128) * (4*D_/128), 256, 0, stream>>>(
        h2_b, wf1_t, b_ffn1, nullptr, nullptr, f1_b, nullptr, nullptr, NROW, 4*D_, D_);
    // G5: t2 = f1 @ w_ffn2 + b_ffn2 + h2(bf16) -> f32
    gemm128_kernel<0,false,true,true,false><<<(NROW/128) * (D_/128), 256, 0, stream>>>(
        f1_b, wf2_t, b_ffn2, h2_b, t2_f, nullptr, nullptr, nullptr, NROW, D_, 4*D_);
    // LN2 -> d_out (f32)
    ln_kernel<true,false><<<NROW/4, 256, 0, stream>>>(t2_f, g2, bn2, (float*)d_out, nullptr);

    (void)in_sizes; (void)n_in; (void)out_size; (void)ws_size;
}

// Round 10
// 263.519 us; speedup vs baseline: 1.8401x; 1.8401x over previous
//
#include <hip/hip_runtime.h>
#include <hip/hip_bf16.h>
#include <math.h>

// ---------------- problem constants ----------------
#define B_   16
#define S_   1024
#define CIN  1280
#define D_   512
#define H_   8
#define HD_  64
#define NROW (B_ * S_)        // 16384

typedef __bf16 bf16;
typedef float  f32x2  __attribute__((ext_vector_type(2)));
typedef float  f32x4  __attribute__((ext_vector_type(4)));
typedef bf16   bf16x4 __attribute__((ext_vector_type(4)));
typedef bf16   bf16x8 __attribute__((ext_vector_type(8)));

__device__ __forceinline__ void gload_lds16(const bf16* g, bf16* l) {
    __builtin_amdgcn_global_load_lds(
        (const __attribute__((address_space(1))) void*)g,
        (__attribute__((address_space(3))) void*)l, 16, 0, 0);
}

#define SBAR()   __builtin_amdgcn_s_barrier()
#define SCHED0() __builtin_amdgcn_sched_barrier(0)
#define VMCNT8() asm volatile("s_waitcnt vmcnt(8)" ::: "memory")
#define VMCNT2() asm volatile("s_waitcnt vmcnt(2)" ::: "memory")
#define VMCNT0() asm volatile("s_waitcnt vmcnt(0)" ::: "memory")

// ---------------- merged preamble: cvt(x) + 5 weight transposes + cs table ----
__device__ __forceinline__ void tr_tile(const float* __restrict__ in,
                                        bf16* __restrict__ out,
                                        int R, int C, int cx, int ry, int t)
{
    __shared__ float T[32][33];
    const int r0 = ry << 5, c0 = cx << 5;
    {
        int lr = t >> 3, lc = (t & 7) << 2;
        f32x4 v = *(const f32x4*)(in + (size_t)(r0 + lr) * C + c0 + lc);
        T[lr][lc] = v[0]; T[lr][lc + 1] = v[1]; T[lr][lc + 2] = v[2]; T[lr][lc + 3] = v[3];
    }
    __syncthreads();
    {
        int oc = t >> 3, orr = (t & 7) << 2;
        bf16x4 o;
        o[0] = (bf16)T[orr][oc];     o[1] = (bf16)T[orr + 1][oc];
        o[2] = (bf16)T[orr + 2][oc]; o[3] = (bf16)T[orr + 3][oc];
        *(bf16x4*)(out + (size_t)(c0 + oc) * R + r0 + orr) = o;
    }
}

#define NCVT (NROW * CIN / 4 / 256)   // 20480 blocks for x cvt

__global__ __launch_bounds__(256)
void prep_kernel(const float* __restrict__ x, bf16* __restrict__ x_b,
                 const float* __restrict__ w_in,   bf16* __restrict__ win_t,
                 const float* __restrict__ w_qkv,  bf16* __restrict__ wqkv_t,
                 const float* __restrict__ w_out,  bf16* __restrict__ wout_t,
                 const float* __restrict__ w_ffn1, bf16* __restrict__ wf1_t,
                 const float* __restrict__ w_ffn2, bf16* __restrict__ wf2_t,
                 float* __restrict__ cs)
{
    const int t   = threadIdx.x;
    int bid = blockIdx.x;
    if (bid < NCVT) {
        int i = bid * 256 + t;
        f32x4 v = *(const f32x4*)(x + (size_t)i * 4);
        bf16x4 o;
        o[0] = (bf16)v[0]; o[1] = (bf16)v[1]; o[2] = (bf16)v[2]; o[3] = (bf16)v[3];
        *(bf16x4*)(x_b + (size_t)i * 4) = o;
        return;
    }
    bid -= NCVT;
    if (bid < 640)  { tr_tile(w_in,   win_t,  1280, 512,  bid % 16, bid / 16, t); return; }
    bid -= 640;
    if (bid < 768)  { tr_tile(w_qkv,  wqkv_t, 512,  1536, bid % 48, bid / 48, t); return; }
    bid -= 768;
    if (bid < 256)  { tr_tile(w_out,  wout_t, 512,  512,  bid % 16, bid / 16, t); return; }
    bid -= 256;
    if (bid < 1024) { tr_tile(w_ffn1, wf1_t,  512,  2048, bid % 64, bid / 64, t); return; }
    bid -= 1024;
    if (bid < 1024) { tr_tile(w_ffn2, wf2_t,  2048, 512,  bid % 16, bid / 16, t); return; }
    bid -= 1024;
    {   // cs table: 128 blocks
        int idx = bid * 256 + t;              // 0..32767
        int s = idx >> 5, i = idx & 31;
        float freq = exp2f(-(float)i * (13.287712379549449f / 32.f));
        float sn, c;
        sincosf((float)s * freq, &sn, &c);
        cs[(size_t)idx * 2]     = c;
        cs[(size_t)idx * 2 + 1] = sn;
    }
}
#define NPREP (NCVT + 640 + 768 + 256 + 1024 + 1024 + 128)

// ---------------- 128x128 BK=64 double-buffered GEMM (ALL five GEMMs) ----------------
#define ASZ1 (128 * 64)

template<int EPI, bool RELU, bool RES, bool OUTF, bool OUTB>
__global__ __launch_bounds__(256, 2)
void gemm128_kernel(const bf16* __restrict__ A, const bf16* __restrict__ Wt,
                    const float* __restrict__ bias, const bf16* __restrict__ res,
                    float* __restrict__ outf, bf16* __restrict__ outb,
                    const float* __restrict__ cs, bf16* __restrict__ vt,
                    int M, int N, int K)
{
    __shared__ bf16 lds[4 * ASZ1];   // A dbuf (2) + B dbuf (2), 64 KiB

    const int tid  = threadIdx.x;
    const int lane = tid & 63;
    const int wid  = tid >> 6;

    const int perX = (M >> 7) >> 3;            // 16
    const int lin  = blockIdx.x;
    const int idx  = lin >> 3;
    const int my   = (lin & 7) * perX + (idx & (perX - 1));
    const int nx   = idx / perX;
    const int m0   = my << 7, n0 = nx << 7;

    const int sRow = lane >> 3;
    const int sK   = ((lane & 7) ^ sRow) << 3;

    const int r2  = wid >> 1;
    const int c2  = wid & 1;
    const int cc  = lane & 15;
    const int g   = (lane >> 4) & 3;
    const int swz = (cc & 7) << 4;

    f32x4 acc[4][4] = {};

    auto stage = [&](int t, int b) {
        const bf16* gA = A  + (size_t)m0 * K + t * 64;
        const bf16* gB = Wt + (size_t)n0 * K + t * 64;
        bf16* lA = lds + b * ASZ1;
        bf16* lB = lds + 2 * ASZ1 + b * ASZ1;
        #pragma unroll
        for (int v = 0; v < 4; ++v) {
            const int ch = v * 4 + wid;
            gload_lds16(gA + (size_t)(ch * 8 + sRow) * K + sK, lA + ch * 512);
            gload_lds16(gB + (size_t)(ch * 8 + sRow) * K + sK, lB + ch * 512);
        }
    };

    const int T = K >> 6;
    stage(0, 0);
    stage(1, 1);
    VMCNT8();
    SCHED0();
    SBAR();

    for (int t = 0; t < T; ++t) {
        const int b = t & 1;
        const char* lA = (const char*)(lds + b * ASZ1);
        const char* lB = (const char*)(lds + 2 * ASZ1 + b * ASZ1);

        #pragma unroll
        for (int ks = 0; ks < 2; ++ks) {
            bf16x8 af[4], bfr[4];
            #pragma unroll
            for (int i = 0; i < 4; ++i) {
                const int row = r2 * 64 + i * 16 + cc;
                af[i] = *(const bf16x8*)(lA + row * 128 + ((ks * 64 + g * 16) ^ swz));
            }
            #pragma unroll
            for (int j = 0; j < 4; ++j) {
                const int row = c2 * 64 + j * 16 + cc;
                bfr[j] = *(const bf16x8*)(lB + row * 128 + ((ks * 64 + g * 16) ^ swz));
            }
            __builtin_amdgcn_s_setprio(1);
            #pragma unroll
            for (int i = 0; i < 4; ++i)
                #pragma unroll
                for (int j = 0; j < 4; ++j)
                    acc[i][j] = __builtin_amdgcn_mfma_f32_16x16x32_bf16(af[i], bfr[j], acc[i][j], 0, 0, 0);
            __builtin_amdgcn_s_setprio(0);
        }
        SCHED0();
        SBAR();
        if (t + 2 < T) {
            stage(t + 2, b);
            VMCNT8();
        } else if (t + 1 < T) {
            VMCNT0();
        }
        if (t + 1 < T) { SCHED0(); SBAR(); }
    }

    const int rq = g << 2;
    if constexpr (EPI == 1) {
        const int colb = c2 * 64;
        if (nx < 8) {
            float bj[4];
            #pragma unroll
            for (int j = 0; j < 4; ++j) bj[j] = bias[n0 + colb + j * 16 + cc];
            #pragma unroll
            for (int i = 0; i < 4; ++i) {
                #pragma unroll
                for (int r = 0; r < 4; ++r) {
                    const int gm = m0 + r2 * 64 + i * 16 + rq + r;
                    const int s  = gm & (S_ - 1);
                    #pragma unroll
                    for (int jp = 0; jp < 2; ++jp) {
                        const int d = jp * 16 + cc;
                        f32x2 csv = *(const f32x2*)(cs + ((size_t)s * 32 + d) * 2);
                        float x1 = acc[i][jp][r]     + bj[jp];
                        float x2 = acc[i][jp + 2][r] + bj[jp + 2];
                        const size_t o1 = (size_t)gm * N + n0 + colb + d;
                        outb[o1]      = (bf16)(x1 * csv[0] - x2 * csv[1]);
                        outb[o1 + 32] = (bf16)(x1 * csv[1] + x2 * csv[0]);
                    }
                }
            }
        } else {
            const int col0 = n0 + colb;
            const int hw = (col0 >> 6) & 7;
            const int bb = m0 >> 10;
            bf16* vbase = vt + (size_t)(bb * 8 + hw) * (HD_ * S_);
            const int sb0 = (m0 & (S_ - 1)) + r2 * 64 + rq;
            #pragma unroll
            for (int i = 0; i < 4; ++i) {
                #pragma unroll
                for (int j = 0; j < 4; ++j) {
                    const int d = j * 16 + cc;
                    const float bv = bias[col0 + d];
                    bf16x4 pk;
                    #pragma unroll
                    for (int r = 0; r < 4; ++r) pk[r] = (bf16)(acc[i][j][r] + bv);
                    *(bf16x4*)(vbase + (size_t)d * S_ + sb0 + i * 16) = pk;
                }
            }
        }
    } else {
        #pragma unroll
        for (int i = 0; i < 4; ++i) {
            #pragma unroll
            for (int j = 0; j < 4; ++j) {
                const int gn = n0 + c2 * 64 + j * 16 + cc;
                const float bv = bias[gn];
                #pragma unroll
                for (int r = 0; r < 4; ++r) {
                    const int gm = m0 + r2 * 64 + i * 16 + rq + r;
                    float v = acc[i][j][r] + bv;
                    if (RES)  v += (float)res[(size_t)gm * N + gn];
                    if (RELU) v = fmaxf(v, 0.f);
                    if (OUTF) outf[(size_t)gm * N + gn] = v;
                    if (OUTB) outb[(size_t)gm * N + gn] = (bf16)v;
                }
            }
        }
    }
    (void)cs; (void)vt;
}

// ---------------- MFMA flash attention v7: round-7 staged structure + trims ----
// 8 waves, QBLK=128, 16 q-rows/wave. K/V^T gload_lds-staged (coalesced 1KB/wave
// — staging IS the coalescer; round-9 showed direct global frags are TA-bound),
// double-buffered, counted vmcnt(2). VALU trims: l via ones-column MFMA (rides
// the defer-max rescale), fma-folded exp2. Defer-max THR=8 lg2. LDS 51200 B.
#define PST 72

__global__ __launch_bounds__(512)
void attn_kernel(const bf16* __restrict__ qkv, const bf16* __restrict__ vtg,
                 bf16* __restrict__ o)
{
    __shared__ bf16 Ks[2][4096];
    __shared__ bf16 Vs[2][4096];
    __shared__ bf16 Ps[8][16 * PST];

    const int bh  = blockIdx.x;
    const int b   = bh >> 3;
    const int h   = bh & 7;
    const int q0  = blockIdx.y << 7;
    const int tid = threadIdx.x;
    const int lane = tid & 63;
    const int w    = tid >> 6;
    const int c    = lane & 15;
    const int g    = lane >> 4;
    const int swz  = (c & 7) << 4;

    const size_t rs = 3 * D_;
    const bf16* qb = qkv + (size_t)b * S_ * rs + h * HD_;
    const bf16* kb = qb + D_;
    const bf16* vt = vtg + (size_t)bh * HD_ * S_;

    const int sRow = tid >> 3;                       // 0..63
    const int sOff = ((tid & 7) ^ (sRow & 7)) << 3;  // pre-swizzled col

    bf16x8 qf[2];
    {
        const bf16* qrow = qb + (size_t)(q0 + w * 16 + c) * rs + g * 8;
        qf[0] = *(const bf16x8*)(qrow);
        qf[1] = *(const bf16x8*)(qrow + 32);
    }
    SCHED0();   // q loads issued before staging (vmcnt ordering)

    bf16x8 vones;
    {
        bf16 one = (bf16)(c == 0 ? 1.f : 0.f);
        #pragma unroll
        for (int u = 0; u < 8; ++u) vones[u] = one;
    }

    auto stage = [&](int t, int buf) {
        gload_lds16(kb + (size_t)(t * 64 + sRow) * rs + sOff, &Ks[buf][0] + (size_t)tid * 8);
        gload_lds16(vt + (size_t)sRow * S_ + t * 64 + sOff,   &Vs[buf][0] + (size_t)tid * 8);
    };

    f32x4 oa[4] = {};
    f32x4 oa5 = {};                          // l rides in col 0 (c==0 lanes)
    float m_r = -3.0e38f;
    const float CE  = 0.18033688011112042f;  // (1/8)*log2(e)
    const float THR = 44.3614195558365f;     // 8 / CE (raw-score units)

    stage(0, 0);
    stage(1, 1);
    VMCNT2();        // q + tile0 landed; tile1's 2 in flight
    SCHED0();
    SBAR();

    for (int t = 0; t < 16; ++t) {
        const int buf = t & 1;
        const char* kB = (const char*)Ks[buf];
        const char* vB = (const char*)Vs[buf];

        // QK^T (swapped): S^T[key][q]
        f32x4 sa[4] = {};
        __builtin_amdgcn_s_setprio(1);
        #pragma unroll
        for (int ch = 0; ch < 2; ++ch)
            #pragma unroll
            for (int ks = 0; ks < 4; ++ks) {
                bf16x8 kf = *(const bf16x8*)(kB + (ks * 16 + c) * 128 + ((ch * 64 + g * 16) ^ swz));
                sa[ks] = __builtin_amdgcn_mfma_f32_16x16x32_bf16(kf, qf[ch], sa[ks], 0, 0, 0);
            }
        __builtin_amdgcn_s_setprio(0);

        float pmax = -3.0e38f;
        #pragma unroll
        for (int ks = 0; ks < 4; ++ks)
            pmax = fmaxf(pmax, fmaxf(fmaxf(sa[ks][0], sa[ks][1]), fmaxf(sa[ks][2], sa[ks][3])));
        pmax = fmaxf(pmax, __shfl_xor(pmax, 16, 64));
        pmax = fmaxf(pmax, __shfl_xor(pmax, 32, 64));

        // defer-max: rescale only when max grew past threshold (wave-uniform)
        if (!__all(pmax - m_r <= THR)) {
            float mnew = fmaxf(m_r, pmax);
            float sc = __builtin_amdgcn_exp2f((m_r - mnew) * CE);
            #pragma unroll
            for (int r = 0; r < 4; ++r) {
                float scr = __shfl(sc, g * 4 + r, 64);
                #pragma unroll
                for (int j = 0; j < 4; ++j) oa[j][r] *= scr;
                oa5[r] *= scr;
            }
            m_r = mnew;
        }

        const float nmCE = -m_r * CE;
        #pragma unroll
        for (int ks = 0; ks < 4; ++ks) {
            bf16x4 pb;
            #pragma unroll
            for (int r = 0; r < 4; ++r)
                pb[r] = (bf16)__builtin_amdgcn_exp2f(__builtin_fmaf(sa[ks][r], CE, nmCE));
            *(bf16x4*)&Ps[w][c * PST + ks * 16 + g * 4] = pb;
        }

        // PV: A = P[q][key], B = V^T[d][key]; l via ones-column
        __builtin_amdgcn_s_setprio(1);
        #pragma unroll
        for (int ch = 0; ch < 2; ++ch) {
            bf16x8 pa = *(const bf16x8*)&Ps[w][c * PST + ch * 32 + g * 8];
            #pragma unroll
            for (int j = 0; j < 4; ++j) {
                bf16x8 vf = *(const bf16x8*)(vB + (j * 16 + c) * 128 + ((ch * 64 + g * 16) ^ swz));
                oa[j] = __builtin_amdgcn_mfma_f32_16x16x32_bf16(pa, vf, oa[j], 0, 0, 0);
            }
            oa5 = __builtin_amdgcn_mfma_f32_16x16x32_bf16(pa, vones, oa5, 0, 0, 0);
        }
        __builtin_amdgcn_s_setprio(0);

        SCHED0();
        SBAR();                              // all waves done reading buf
        if (t + 2 < 16) {
            stage(t + 2, buf);
            VMCNT2();                        // tile t+1 landed; t+2 in flight
        } else if (t + 1 < 16) {
            VMCNT0();
        }
        if (t + 1 < 16) { SCHED0(); SBAR(); }
    }

    float linv[4];
    #pragma unroll
    for (int r = 0; r < 4; ++r)
        linv[r] = 1.f / __shfl(oa5[r], lane & 48, 64);   // l from (c=0, same g)
    #pragma unroll
    for (int j = 0; j < 4; ++j)
        #pragma unroll
        for (int r = 0; r < 4; ++r) {
            int q = q0 + w * 16 + g * 4 + r;
            o[((size_t)(b * S_) + q) * D_ + h * HD_ + j * 16 + c] = (bf16)(oa[j][r] * linv[r]);
        }
}

// ---------------- LayerNorm over D=512, one wave per row ----------------
template<bool OUTF, bool OUTB>
__global__ __launch_bounds__(256)
void ln_kernel(const float* __restrict__ in, const float* __restrict__ g,
               const float* __restrict__ be, float* __restrict__ outf,
               bf16* __restrict__ outb)
{
    const int row  = (blockIdx.x << 2) + (threadIdx.x >> 6);
    const int lane = threadIdx.x & 63;
    const float* p = in + (size_t)row * D_;
    f32x4 a  = *(const f32x4*)(p + lane * 4);
    f32x4 b2 = *(const f32x4*)(p + 256 + lane * 4);
    float s  = a[0] + a[1] + a[2] + a[3] + b2[0] + b2[1] + b2[2] + b2[3];
    float s2 = a[0]*a[0] + a[1]*a[1] + a[2]*a[2] + a[3]*a[3]
             + b2[0]*b2[0] + b2[1]*b2[1] + b2[2]*b2[2] + b2[3]*b2[3];
    #pragma unroll
    for (int off = 32; off; off >>= 1) {
        s  += __shfl_xor(s,  off, 64);
        s2 += __shfl_xor(s2, off, 64);
    }
    const float mean = s * (1.f / 512.f);
    const float var  = s2 * (1.f / 512.f) - mean * mean;
    const float rstd = rsqrtf(var + 1e-5f);

    f32x4 g0 = *(const f32x4*)(g + lane * 4);
    f32x4 g1 = *(const f32x4*)(g + 256 + lane * 4);
    f32x4 e0 = *(const f32x4*)(be + lane * 4);
    f32x4 e1 = *(const f32x4*)(be + 256 + lane * 4);
    f32x4 o0, o1;
    #pragma unroll
    for (int u = 0; u < 4; u++) {
        o0[u] = (a[u]  - mean) * rstd * g0[u] + e0[u];
        o1[u] = (b2[u] - mean) * rstd * g1[u] + e1[u];
    }
    if (OUTF) {
        float* of = outf + (size_t)row * D_;
        *(f32x4*)(of + lane * 4)       = o0;
        *(f32x4*)(of + 256 + lane * 4) = o1;
    }
    if (OUTB) {
        bf16x4 c0, c1;
        #pragma unroll
        for (int u = 0; u < 4; u++) { c0[u] = (bf16)o0[u]; c1[u] = (bf16)o1[u]; }
        bf16* ob = outb + (size_t)row * D_;
        *(bf16x4*)(ob + lane * 4)       = c0;
        *(bf16x4*)(ob + 256 + lane * 4) = c1;
    }
}

// ---------------- host launcher ----------------
extern "C" void kernel_launch(void* const* d_in, const int* in_sizes, int n_in,
                              void* d_out, int out_size, void* d_ws, size_t ws_size,
                              hipStream_t stream)
{
    const float* x      = (const float*)d_in[0];
    const float* w_in   = (const float*)d_in[1];
    const float* b_in   = (const float*)d_in[2];
    const float* w_qkv  = (const float*)d_in[3];
    const float* b_qkv  = (const float*)d_in[4];
    const float* w_out  = (const float*)d_in[5];
    const float* b_out  = (const float*)d_in[6];
    const float* w_ffn1 = (const float*)d_in[7];
    const float* b_ffn1 = (const float*)d_in[8];
    const float* w_ffn2 = (const float*)d_in[9];
    const float* b_ffn2 = (const float*)d_in[10];
    const float* g1     = (const float*)d_in[11];
    const float* bn1    = (const float*)d_in[12];
    const float* g2     = (const float*)d_in[13];
    const float* bn2    = (const float*)d_in[14];

    char* ws = (char*)d_ws;
    constexpr size_t OFF_XB   = 0;
    constexpr size_t OFF_WIN  = OFF_XB   + 41943040ull;
    constexpr size_t OFF_WQKV = OFF_WIN  + 1310720ull;
    constexpr size_t OFF_WOUT = OFF_WQKV + 1572864ull;
    constexpr size_t OFF_WF1  = OFF_WOUT + 524288ull;
    constexpr size_t OFF_WF2  = OFF_WF1  + 2097152ull;
    constexpr size_t OFF_CS   = OFF_WF2  + 2097152ull;
    constexpr size_t OFF_HB   = OFF_CS   + 33554432ull;
    constexpr size_t OFF_QKV  = OFF_HB   + 16777216ull;
    constexpr size_t OFF_OB   = OFF_QKV  + 50331648ull;
    constexpr size_t OFF_VT   = OFF_OB   + 16777216ull;
    constexpr size_t OFF_H2B  = OFF_VT   + 33554432ull;
    constexpr size_t OFF_F1   = OFF_H2B  + 16777216ull;
    constexpr size_t OFF_T1   = OFF_XB;
    constexpr size_t OFF_T2   = OFF_QKV;

    bf16*  x_b    = (bf16*)(ws + OFF_XB);
    bf16*  win_t  = (bf16*)(ws + OFF_WIN);
    bf16*  wqkv_t = (bf16*)(ws + OFF_WQKV);
    bf16*  wout_t = (bf16*)(ws + OFF_WOUT);
    bf16*  wf1_t  = (bf16*)(ws + OFF_WF1);
    bf16*  wf2_t  = (bf16*)(ws + OFF_WF2);
    float* cs_t   = (float*)(ws + OFF_CS);
    bf16*  h_b    = (bf16*)(ws + OFF_HB);
    bf16*  qkv_b  = (bf16*)(ws + OFF_QKV);
    bf16*  o_b    = (bf16*)(ws + OFF_OB);
    bf16*  vt_g   = (bf16*)(ws + OFF_VT);
    bf16*  h2_b   = (bf16*)(ws + OFF_H2B);
    bf16*  f1_b   = (bf16*)(ws + OFF_F1);
    float* t1_f   = (float*)(ws + OFF_T1);
    float* t2_f   = (float*)(ws + OFF_T2);

    // merged preamble (1 launch)
    prep_kernel<<<NPREP, 256, 0, stream>>>(x, x_b, w_in, win_t, w_qkv, wqkv_t,
                                           w_out, wout_t, w_ffn1, wf1_t,
                                           w_ffn2, wf2_t, cs_t);

    // G1: h = x @ w_in + b_in -> bf16
    gemm128_kernel<0,false,false,false,true><<<(NROW/128) * (D_/128), 256, 0, stream>>>(
        x_b, win_t, b_in, nullptr, nullptr, h_b, nullptr, nullptr, NROW, D_, CIN);
    // G2: qkv = h @ w_qkv + b_qkv; fused RoPE(q,k)->qkv_b, v->vt_g
    gemm128_kernel<1,false,false,false,true><<<(NROW/128) * (3*D_/128), 256, 0, stream>>>(
        h_b, wqkv_t, b_qkv, nullptr, nullptr, qkv_b, cs_t, vt_g, NROW, 3*D_, D_);
    // attention -> o bf16   (QBLK=128, staged, 8 waves)
    attn_kernel<<<dim3(B_*H_, S_/128), 512, 0, stream>>>(qkv_b, vt_g, o_b);
    // G3: t1 = o @ w_out + b_out + h(bf16) -> f32
    gemm128_kernel<0,false,true,true,false><<<(NROW/128) * (D_/128), 256, 0, stream>>>(
        o_b, wout_t, b_out, h_b, t1_f, nullptr, nullptr, nullptr, NROW, D_, D_);
    // LN1 -> h2 bf16
    ln_kernel<false,true><<<NROW/4, 256, 0, stream>>>(t1_f, g1, bn1, nullptr, h2_b);
    // G4: f1 = relu(h2 @ w_ffn1 + b_ffn1) -> bf16
    gemm128_kernel<0,true,false,false,true><<<(NROW/128) * (4*D_/128), 256, 0, stream>>>(
        h2_b, wf1_t, b_ffn1, nullptr, nullptr, f1_b, nullptr, nullptr, NROW, 4*D_, D_);
    // G5: t2 = f1 @ w_ffn2 + b_ffn2 + h2(bf16) -> f32
    gemm128_kernel<0,false,true,true,false><<<(NROW/128) * (D_/128), 256, 0, stream>>>(
        f1_b, wf2_t, b_ffn2, h2_b, t2_f, nullptr, nullptr, nullptr, NROW, D_, 4*D_);
    // LN2 -> d_out (f32)
    ln_kernel<true,false><<<NROW/4, 256, 0, stream>>>(t2_f, g2, bn2, (float*)d_out, nullptr);

    (void)in_sizes; (void)n_in; (void)out_size; (void)ws_size;
}

// Round 11
// 258.379 us; speedup vs baseline: 1.8767x; 1.0199x over previous
//
#include <hip/hip_runtime.h>
#include <hip/hip_bf16.h>
#include <math.h>

// ---------------- problem constants ----------------
#define B_   16
#define S_   1024
#define CIN  1280
#define D_   512
#define H_   8
#define HD_  64
#define NROW (B_ * S_)        // 16384

typedef __bf16 bf16;
typedef float  f32x2  __attribute__((ext_vector_type(2)));
typedef float  f32x4  __attribute__((ext_vector_type(4)));
typedef bf16   bf16x4 __attribute__((ext_vector_type(4)));
typedef bf16   bf16x8 __attribute__((ext_vector_type(8)));

__device__ __forceinline__ void gload_lds16(const bf16* g, bf16* l) {
    __builtin_amdgcn_global_load_lds(
        (const __attribute__((address_space(1))) void*)g,
        (__attribute__((address_space(3))) void*)l, 16, 0, 0);
}

#define SBAR()   __builtin_amdgcn_s_barrier()
#define SCHED0() __builtin_amdgcn_sched_barrier(0)
#define VMCNT8() asm volatile("s_waitcnt vmcnt(8)" ::: "memory")
#define VMCNT2() asm volatile("s_waitcnt vmcnt(2)" ::: "memory")
#define VMCNT0() asm volatile("s_waitcnt vmcnt(0)" ::: "memory")

// ---------------- merged preamble: cvt(x) + 5 weight transposes + cs table ----
__device__ __forceinline__ void tr_tile(const float* __restrict__ in,
                                        bf16* __restrict__ out,
                                        int R, int C, int cx, int ry, int t)
{
    __shared__ float T[32][33];
    const int r0 = ry << 5, c0 = cx << 5;
    {
        int lr = t >> 3, lc = (t & 7) << 2;
        f32x4 v = *(const f32x4*)(in + (size_t)(r0 + lr) * C + c0 + lc);
        T[lr][lc] = v[0]; T[lr][lc + 1] = v[1]; T[lr][lc + 2] = v[2]; T[lr][lc + 3] = v[3];
    }
    __syncthreads();
    {
        int oc = t >> 3, orr = (t & 7) << 2;
        bf16x4 o;
        o[0] = (bf16)T[orr][oc];     o[1] = (bf16)T[orr + 1][oc];
        o[2] = (bf16)T[orr + 2][oc]; o[3] = (bf16)T[orr + 3][oc];
        *(bf16x4*)(out + (size_t)(c0 + oc) * R + r0 + orr) = o;
    }
}

#define NCVT (NROW * CIN / 4 / 256)   // 20480 blocks for x cvt

__global__ __launch_bounds__(256)
void prep_kernel(const float* __restrict__ x, bf16* __restrict__ x_b,
                 const float* __restrict__ w_in,   bf16* __restrict__ win_t,
                 const float* __restrict__ w_qkv,  bf16* __restrict__ wqkv_t,
                 const float* __restrict__ w_out,  bf16* __restrict__ wout_t,
                 const float* __restrict__ w_ffn1, bf16* __restrict__ wf1_t,
                 const float* __restrict__ w_ffn2, bf16* __restrict__ wf2_t,
                 float* __restrict__ cs)
{
    const int t   = threadIdx.x;
    int bid = blockIdx.x;
    if (bid < NCVT) {
        int i = bid * 256 + t;
        f32x4 v = *(const f32x4*)(x + (size_t)i * 4);
        bf16x4 o;
        o[0] = (bf16)v[0]; o[1] = (bf16)v[1]; o[2] = (bf16)v[2]; o[3] = (bf16)v[3];
        *(bf16x4*)(x_b + (size_t)i * 4) = o;
        return;
    }
    bid -= NCVT;
    if (bid < 640)  { tr_tile(w_in,   win_t,  1280, 512,  bid % 16, bid / 16, t); return; }
    bid -= 640;
    if (bid < 768)  { tr_tile(w_qkv,  wqkv_t, 512,  1536, bid % 48, bid / 48, t); return; }
    bid -= 768;
    if (bid < 256)  { tr_tile(w_out,  wout_t, 512,  512,  bid % 16, bid / 16, t); return; }
    bid -= 256;
    if (bid < 1024) { tr_tile(w_ffn1, wf1_t,  512,  2048, bid % 64, bid / 64, t); return; }
    bid -= 1024;
    if (bid < 1024) { tr_tile(w_ffn2, wf2_t,  2048, 512,  bid % 16, bid / 16, t); return; }
    bid -= 1024;
    {   // cs table: 128 blocks
        int idx = bid * 256 + t;              // 0..32767
        int s = idx >> 5, i = idx & 31;
        float freq = exp2f(-(float)i * (13.287712379549449f / 32.f));
        float sn, c;
        sincosf((float)s * freq, &sn, &c);
        cs[(size_t)idx * 2]     = c;
        cs[(size_t)idx * 2 + 1] = sn;
    }
}
#define NPREP (NCVT + 640 + 768 + 256 + 1024 + 1024 + 128)

// ---------------- 128x128 BK=64 double-buffered GEMM (ALL five GEMMs) ----------------
#define ASZ1 (128 * 64)

template<int EPI, bool RELU, bool RES, bool OUTF, bool OUTB>
__global__ __launch_bounds__(256, 2)
void gemm128_kernel(const bf16* __restrict__ A, const bf16* __restrict__ Wt,
                    const float* __restrict__ bias, const bf16* __restrict__ res,
                    float* __restrict__ outf, bf16* __restrict__ outb,
                    const float* __restrict__ cs, bf16* __restrict__ vt,
                    int M, int N, int K)
{
    __shared__ bf16 lds[4 * ASZ1];   // A dbuf (2) + B dbuf (2), 64 KiB

    const int tid  = threadIdx.x;
    const int lane = tid & 63;
    const int wid  = tid >> 6;

    const int perX = (M >> 7) >> 3;            // 16
    const int lin  = blockIdx.x;
    const int idx  = lin >> 3;
    const int my   = (lin & 7) * perX + (idx & (perX - 1));
    const int nx   = idx / perX;
    const int m0   = my << 7, n0 = nx << 7;

    const int sRow = lane >> 3;
    const int sK   = ((lane & 7) ^ sRow) << 3;

    const int r2  = wid >> 1;
    const int c2  = wid & 1;
    const int cc  = lane & 15;
    const int g   = (lane >> 4) & 3;
    const int swz = (cc & 7) << 4;

    f32x4 acc[4][4] = {};

    auto stage = [&](int t, int b) {
        const bf16* gA = A  + (size_t)m0 * K + t * 64;
        const bf16* gB = Wt + (size_t)n0 * K + t * 64;
        bf16* lA = lds + b * ASZ1;
        bf16* lB = lds + 2 * ASZ1 + b * ASZ1;
        #pragma unroll
        for (int v = 0; v < 4; ++v) {
            const int ch = v * 4 + wid;
            gload_lds16(gA + (size_t)(ch * 8 + sRow) * K + sK, lA + ch * 512);
            gload_lds16(gB + (size_t)(ch * 8 + sRow) * K + sK, lB + ch * 512);
        }
    };

    const int T = K >> 6;
    stage(0, 0);
    stage(1, 1);
    VMCNT8();
    SCHED0();
    SBAR();

    for (int t = 0; t < T; ++t) {
        const int b = t & 1;
        const char* lA = (const char*)(lds + b * ASZ1);
        const char* lB = (const char*)(lds + 2 * ASZ1 + b * ASZ1);

        #pragma unroll
        for (int ks = 0; ks < 2; ++ks) {
            bf16x8 af[4], bfr[4];
            #pragma unroll
            for (int i = 0; i < 4; ++i) {
                const int row = r2 * 64 + i * 16 + cc;
                af[i] = *(const bf16x8*)(lA + row * 128 + ((ks * 64 + g * 16) ^ swz));
            }
            #pragma unroll
            for (int j = 0; j < 4; ++j) {
                const int row = c2 * 64 + j * 16 + cc;
                bfr[j] = *(const bf16x8*)(lB + row * 128 + ((ks * 64 + g * 16) ^ swz));
            }
            __builtin_amdgcn_s_setprio(1);
            #pragma unroll
            for (int i = 0; i < 4; ++i)
                #pragma unroll
                for (int j = 0; j < 4; ++j)
                    acc[i][j] = __builtin_amdgcn_mfma_f32_16x16x32_bf16(af[i], bfr[j], acc[i][j], 0, 0, 0);
            __builtin_amdgcn_s_setprio(0);
        }
        SCHED0();
        SBAR();
        if (t + 2 < T) {
            stage(t + 2, b);
            VMCNT8();
        } else if (t + 1 < T) {
            VMCNT0();
        }
        if (t + 1 < T) { SCHED0(); SBAR(); }
    }

    const int rq = g << 2;
    if constexpr (EPI == 1) {
        const int colb = c2 * 64;
        if (nx < 8) {
            float bj[4];
            #pragma unroll
            for (int j = 0; j < 4; ++j) bj[j] = bias[n0 + colb + j * 16 + cc];
            #pragma unroll
            for (int i = 0; i < 4; ++i) {
                #pragma unroll
                for (int r = 0; r < 4; ++r) {
                    const int gm = m0 + r2 * 64 + i * 16 + rq + r;
                    const int s  = gm & (S_ - 1);
                    #pragma unroll
                    for (int jp = 0; jp < 2; ++jp) {
                        const int d = jp * 16 + cc;
                        f32x2 csv = *(const f32x2*)(cs + ((size_t)s * 32 + d) * 2);
                        float x1 = acc[i][jp][r]     + bj[jp];
                        float x2 = acc[i][jp + 2][r] + bj[jp + 2];
                        const size_t o1 = (size_t)gm * N + n0 + colb + d;
                        outb[o1]      = (bf16)(x1 * csv[0] - x2 * csv[1]);
                        outb[o1 + 32] = (bf16)(x1 * csv[1] + x2 * csv[0]);
                    }
                }
            }
        } else {
            const int col0 = n0 + colb;
            const int hw = (col0 >> 6) & 7;
            const int bb = m0 >> 10;
            bf16* vbase = vt + (size_t)(bb * 8 + hw) * (HD_ * S_);
            const int sb0 = (m0 & (S_ - 1)) + r2 * 64 + rq;
            #pragma unroll
            for (int i = 0; i < 4; ++i) {
                #pragma unroll
                for (int j = 0; j < 4; ++j) {
                    const int d = j * 16 + cc;
                    const float bv = bias[col0 + d];
                    bf16x4 pk;
                    #pragma unroll
                    for (int r = 0; r < 4; ++r) pk[r] = (bf16)(acc[i][j][r] + bv);
                    *(bf16x4*)(vbase + (size_t)d * S_ + sb0 + i * 16) = pk;
                }
            }
        }
    } else {
        #pragma unroll
        for (int i = 0; i < 4; ++i) {
            #pragma unroll
            for (int j = 0; j < 4; ++j) {
                const int gn = n0 + c2 * 64 + j * 16 + cc;
                const float bv = bias[gn];
                #pragma unroll
                for (int r = 0; r < 4; ++r) {
                    const int gm = m0 + r2 * 64 + i * 16 + rq + r;
                    float v = acc[i][j][r] + bv;
                    if (RES)  v += (float)res[(size_t)gm * N + gn];
                    if (RELU) v = fmaxf(v, 0.f);
                    if (OUTF) outf[(size_t)gm * N + gn] = v;
                    if (OUTB) outb[(size_t)gm * N + gn] = (bf16)v;
                }
            }
        }
    }
    (void)cs; (void)vt;
}

// ---------------- MFMA flash attention v8: triple-buffer, 1 barrier/tile ----
// 8 waves, QBLK=128. stage(t+2) issued at TOP of iter t: buffer (t+2)%3 held
// tile t-1, whose readers all passed the end-of-iter-(t-1) barrier -> no race.
// Each iter ends with vmcnt(2) (own t+1 loads landed; t+2 in flight) + SBAR.
// 16+1 barriers/block vs 32 before; staging issue overlaps whole tile compute.
// l via ones-column MFMA; defer-max THR=8 lg2; fma-folded exp2. LDS 67584 B.
#define PST 72

__global__ __launch_bounds__(512)
void attn_kernel(const bf16* __restrict__ qkv, const bf16* __restrict__ vtg,
                 bf16* __restrict__ o)
{
    __shared__ bf16 Ks[3][4096];
    __shared__ bf16 Vs[3][4096];
    __shared__ bf16 Ps[8][16 * PST];

    const int bh  = blockIdx.x;
    const int b   = bh >> 3;
    const int h   = bh & 7;
    const int q0  = blockIdx.y << 7;
    const int tid = threadIdx.x;
    const int lane = tid & 63;
    const int w    = tid >> 6;
    const int c    = lane & 15;
    const int g    = lane >> 4;
    const int swz  = (c & 7) << 4;

    const size_t rs = 3 * D_;
    const bf16* qb = qkv + (size_t)b * S_ * rs + h * HD_;
    const bf16* kb = qb + D_;
    const bf16* vt = vtg + (size_t)bh * HD_ * S_;

    const int sRow = tid >> 3;                       // 0..63
    const int sOff = ((tid & 7) ^ (sRow & 7)) << 3;  // pre-swizzled col

    bf16x8 qf[2];
    {
        const bf16* qrow = qb + (size_t)(q0 + w * 16 + c) * rs + g * 8;
        qf[0] = *(const bf16x8*)(qrow);
        qf[1] = *(const bf16x8*)(qrow + 32);
    }
    SCHED0();   // q loads issued before staging (vmcnt ordering)

    bf16x8 vones;
    {
        bf16 one = (bf16)(c == 0 ? 1.f : 0.f);
        #pragma unroll
        for (int u = 0; u < 8; ++u) vones[u] = one;
    }

    auto stage = [&](int t, int buf) {
        gload_lds16(kb + (size_t)(t * 64 + sRow) * rs + sOff, &Ks[buf][0] + (size_t)tid * 8);
        gload_lds16(vt + (size_t)sRow * S_ + t * 64 + sOff,   &Vs[buf][0] + (size_t)tid * 8);
    };

    f32x4 oa[4] = {};
    f32x4 oa5 = {};                          // l rides in col 0 (c==0 lanes)
    float m_r = -3.0e38f;
    const float CE  = 0.18033688011112042f;  // (1/8)*log2(e)
    const float THR = 44.3614195558365f;     // 8 / CE (raw-score units)

    stage(0, 0);
    stage(1, 1);
    VMCNT2();        // q + tile0 landed; tile1's 2 in flight
    SCHED0();
    SBAR();

    for (int t = 0; t < 16; ++t) {
        const int buf = t % 3;
        // issue tile t+2 into the buffer tile t-1 just vacated (barrier-separated)
        if (t + 2 < 16) stage(t + 2, (t + 2) % 3);

        const char* kB = (const char*)&Ks[buf][0];
        const char* vB = (const char*)&Vs[buf][0];

        // QK^T (swapped): S^T[key][q]
        f32x4 sa[4] = {};
        __builtin_amdgcn_s_setprio(1);
        #pragma unroll
        for (int ch = 0; ch < 2; ++ch)
            #pragma unroll
            for (int ks = 0; ks < 4; ++ks) {
                bf16x8 kf = *(const bf16x8*)(kB + (ks * 16 + c) * 128 + ((ch * 64 + g * 16) ^ swz));
                sa[ks] = __builtin_amdgcn_mfma_f32_16x16x32_bf16(kf, qf[ch], sa[ks], 0, 0, 0);
            }
        __builtin_amdgcn_s_setprio(0);

        float pmax = -3.0e38f;
        #pragma unroll
        for (int ks = 0; ks < 4; ++ks)
            pmax = fmaxf(pmax, fmaxf(fmaxf(sa[ks][0], sa[ks][1]), fmaxf(sa[ks][2], sa[ks][3])));
        pmax = fmaxf(pmax, __shfl_xor(pmax, 16, 64));
        pmax = fmaxf(pmax, __shfl_xor(pmax, 32, 64));

        // defer-max: rescale only when max grew past threshold (wave-uniform)
        if (!__all(pmax - m_r <= THR)) {
            float mnew = fmaxf(m_r, pmax);
            float sc = __builtin_amdgcn_exp2f((m_r - mnew) * CE);
            #pragma unroll
            for (int r = 0; r < 4; ++r) {
                float scr = __shfl(sc, g * 4 + r, 64);
                #pragma unroll
                for (int j = 0; j < 4; ++j) oa[j][r] *= scr;
                oa5[r] *= scr;
            }
            m_r = mnew;
        }

        const float nmCE = -m_r * CE;
        #pragma unroll
        for (int ks = 0; ks < 4; ++ks) {
            bf16x4 pb;
            #pragma unroll
            for (int r = 0; r < 4; ++r)
                pb[r] = (bf16)__builtin_amdgcn_exp2f(__builtin_fmaf(sa[ks][r], CE, nmCE));
            *(bf16x4*)&Ps[w][c * PST + ks * 16 + g * 4] = pb;
        }

        // PV: A = P[q][key], B = V^T[d][key]; l via ones-column
        __builtin_amdgcn_s_setprio(1);
        #pragma unroll
        for (int ch = 0; ch < 2; ++ch) {
            bf16x8 pa = *(const bf16x8*)&Ps[w][c * PST + ch * 32 + g * 8];
            #pragma unroll
            for (int j = 0; j < 4; ++j) {
                bf16x8 vf = *(const bf16x8*)(vB + (j * 16 + c) * 128 + ((ch * 64 + g * 16) ^ swz));
                oa[j] = __builtin_amdgcn_mfma_f32_16x16x32_bf16(pa, vf, oa[j], 0, 0, 0);
            }
            oa5 = __builtin_amdgcn_mfma_f32_16x16x32_bf16(pa, vones, oa5, 0, 0, 0);
        }
        __builtin_amdgcn_s_setprio(0);

        SCHED0();
        if (t + 1 < 16) {
            if (t + 2 < 16) { VMCNT2(); } else { VMCNT0(); }   // own t+1 loads landed
            SBAR();                                            // publish to all waves
        }
    }

    float linv[4];
    #pragma unroll
    for (int r = 0; r < 4; ++r)
        linv[r] = 1.f / __shfl(oa5[r], lane & 48, 64);   // l from (c=0, same g)
    #pragma unroll
    for (int j = 0; j < 4; ++j)
        #pragma unroll
        for (int r = 0; r < 4; ++r) {
            int q = q0 + w * 16 + g * 4 + r;
            o[((size_t)(b * S_) + q) * D_ + h * HD_ + j * 16 + c] = (bf16)(oa[j][r] * linv[r]);
        }
}

// ---------------- LayerNorm over D=512, bf16 input, one wave per row ----------------
template<bool OUTF, bool OUTB>
__global__ __launch_bounds__(256)
void ln_kernel(const bf16* __restrict__ in, const float* __restrict__ g,
               const float* __restrict__ be, float* __restrict__ outf,
               bf16* __restrict__ outb)
{
    const int row  = (blockIdx.x << 2) + (threadIdx.x >> 6);
    const int lane = threadIdx.x & 63;
    const bf16* p = in + (size_t)row * D_ + lane * 8;
    bf16x8 raw = *(const bf16x8*)p;
    float v[8];
    float s = 0.f, s2 = 0.f;
    #pragma unroll
    for (int u = 0; u < 8; ++u) {
        v[u] = (float)raw[u];
        s  += v[u];
        s2 += v[u] * v[u];
    }
    #pragma unroll
    for (int off = 32; off; off >>= 1) {
        s  += __shfl_xor(s,  off, 64);
        s2 += __shfl_xor(s2, off, 64);
    }
    const float mean = s * (1.f / 512.f);
    const float var  = s2 * (1.f / 512.f) - mean * mean;
    const float rstd = rsqrtf(var + 1e-5f);

    f32x4 g0 = *(const f32x4*)(g + lane * 8);
    f32x4 g1 = *(const f32x4*)(g + lane * 8 + 4);
    f32x4 e0 = *(const f32x4*)(be + lane * 8);
    f32x4 e1 = *(const f32x4*)(be + lane * 8 + 4);
    float ov[8];
    #pragma unroll
    for (int u = 0; u < 4; ++u) {
        ov[u]     = (v[u]     - mean) * rstd * g0[u] + e0[u];
        ov[u + 4] = (v[u + 4] - mean) * rstd * g1[u] + e1[u];
    }
    if (OUTF) {
        float* of = outf + (size_t)row * D_ + lane * 8;
        f32x4 o0, o1;
        #pragma unroll
        for (int u = 0; u < 4; ++u) { o0[u] = ov[u]; o1[u] = ov[u + 4]; }
        *(f32x4*)(of)     = o0;
        *(f32x4*)(of + 4) = o1;
    }
    if (OUTB) {
        bf16x8 ob;
        #pragma unroll
        for (int u = 0; u < 8; ++u) ob[u] = (bf16)ov[u];
        *(bf16x8*)(outb + (size_t)row * D_ + lane * 8) = ob;
    }
}

// ---------------- host launcher ----------------
extern "C" void kernel_launch(void* const* d_in, const int* in_sizes, int n_in,
                              void* d_out, int out_size, void* d_ws, size_t ws_size,
                              hipStream_t stream)
{
    const float* x      = (const float*)d_in[0];
    const float* w_in   = (const float*)d_in[1];
    const float* b_in   = (const float*)d_in[2];
    const float* w_qkv  = (const float*)d_in[3];
    const float* b_qkv  = (const float*)d_in[4];
    const float* w_out  = (const float*)d_in[5];
    const float* b_out  = (const float*)d_in[6];
    const float* w_ffn1 = (const float*)d_in[7];
    const float* b_ffn1 = (const float*)d_in[8];
    const float* w_ffn2 = (const float*)d_in[9];
    const float* b_ffn2 = (const float*)d_in[10];
    const float* g1     = (const float*)d_in[11];
    const float* bn1    = (const float*)d_in[12];
    const float* g2     = (const float*)d_in[13];
    const float* bn2    = (const float*)d_in[14];

    char* ws = (char*)d_ws;
    constexpr size_t OFF_XB   = 0;
    constexpr size_t OFF_WIN  = OFF_XB   + 41943040ull;
    constexpr size_t OFF_WQKV = OFF_WIN  + 1310720ull;
    constexpr size_t OFF_WOUT = OFF_WQKV + 1572864ull;
    constexpr size_t OFF_WF1  = OFF_WOUT + 524288ull;
    constexpr size_t OFF_WF2  = OFF_WF1  + 2097152ull;
    constexpr size_t OFF_CS   = OFF_WF2  + 2097152ull;
    constexpr size_t OFF_HB   = OFF_CS   + 33554432ull;
    constexpr size_t OFF_QKV  = OFF_HB   + 16777216ull;
    constexpr size_t OFF_OB   = OFF_QKV  + 50331648ull;
    constexpr size_t OFF_VT   = OFF_OB   + 16777216ull;
    constexpr size_t OFF_H2B  = OFF_VT   + 33554432ull;
    constexpr size_t OFF_F1   = OFF_H2B  + 16777216ull;
    constexpr size_t OFF_T1   = OFF_XB;     // t1 bf16 aliases x_b (dead after G1)
    constexpr size_t OFF_T2   = OFF_QKV;    // t2 bf16 aliases qkv_b (dead after attn)

    bf16*  x_b    = (bf16*)(ws + OFF_XB);
    bf16*  win_t  = (bf16*)(ws + OFF_WIN);
    bf16*  wqkv_t = (bf16*)(ws + OFF_WQKV);
    bf16*  wout_t = (bf16*)(ws + OFF_WOUT);
    bf16*  wf1_t  = (bf16*)(ws + OFF_WF1);
    bf16*  wf2_t  = (bf16*)(ws + OFF_WF2);
    float* cs_t   = (float*)(ws + OFF_CS);
    bf16*  h_b    = (bf16*)(ws + OFF_HB);
    bf16*  qkv_b  = (bf16*)(ws + OFF_QKV);
    bf16*  o_b    = (bf16*)(ws + OFF_OB);
    bf16*  vt_g   = (bf16*)(ws + OFF_VT);
    bf16*  h2_b   = (bf16*)(ws + OFF_H2B);
    bf16*  f1_b   = (bf16*)(ws + OFF_F1);
    bf16*  t1_b   = (bf16*)(ws + OFF_T1);
    bf16*  t2_b   = (bf16*)(ws + OFF_T2);

    // merged preamble (1 launch)
    prep_kernel<<<NPREP, 256, 0, stream>>>(x, x_b, w_in, win_t, w_qkv, wqkv_t,
                                           w_out, wout_t, w_ffn1, wf1_t,
                                           w_ffn2, wf2_t, cs_t);

    // G1: h = x @ w_in + b_in -> bf16
    gemm128_kernel<0,false,false,false,true><<<(NROW/128) * (D_/128), 256, 0, stream>>>(
        x_b, win_t, b_in, nullptr, nullptr, h_b, nullptr, nullptr, NROW, D_, CIN);
    // G2: qkv = h @ w_qkv + b_qkv; fused RoPE(q,k)->qkv_b, v->vt_g
    gemm128_kernel<1,false,false,false,true><<<(NROW/128) * (3*D_/128), 256, 0, stream>>>(
        h_b, wqkv_t, b_qkv, nullptr, nullptr, qkv_b, cs_t, vt_g, NROW, 3*D_, D_);
    // attention -> o bf16   (QBLK=128, triple-buffered, 1 barrier/tile)
    attn_kernel<<<dim3(B_*H_, S_/128), 512, 0, stream>>>(qkv_b, vt_g, o_b);
    // G3: t1 = o @ w_out + b_out + h(bf16) -> bf16
    gemm128_kernel<0,false,true,false,true><<<(NROW/128) * (D_/128), 256, 0, stream>>>(
        o_b, wout_t, b_out, h_b, nullptr, t1_b, nullptr, nullptr, NROW, D_, D_);
    // LN1 (bf16 in) -> h2 bf16
    ln_kernel<false,true><<<NROW/4, 256, 0, stream>>>(t1_b, g1, bn1, nullptr, h2_b);
    // G4: f1 = relu(h2 @ w_ffn1 + b_ffn1) -> bf16
    gemm128_kernel<0,true,false,false,true><<<(NROW/128) * (4*D_/128), 256, 0, stream>>>(
        h2_b, wf1_t, b_ffn1, nullptr, nullptr, f1_b, nullptr, nullptr, NROW, 4*D_, D_);
    // G5: t2 = f1 @ w_ffn2 + b_ffn2 + h2(bf16) -> bf16
    gemm128_kernel<0,false,true,false,true><<<(NROW/128) * (D_/128), 256, 0, stream>>>(
        f1_b, wf2_t, b_ffn2, h2_b, nullptr, t2_b, nullptr, nullptr, NROW, D_, 4*D_);
    // LN2 (bf16 in) -> d_out (f32)
    ln_kernel<true,false><<<NROW/4, 256, 0, stream>>>(t2_b, g2, bn2, (float*)d_out, nullptr);

    (void)in_sizes; (void)n_in; (void)out_size; (void)ws_size;
}